// Round 15
// baseline (610.472 us; speedup 1.0000x reference)
//
#include <hip/hip_runtime.h>
#include <cstdint>
#include <cstddef>

#define NN   50000
#define EE   800000
#define ETOT (EE + NN)
#define HC   256
#define NEG_SLOPE 0.2f
#define SENT_WORDS 25000
#define SENT_VAL 0x42C80000u

typedef __attribute__((ext_vector_type(8))) short g4_bf16x8;
typedef __attribute__((ext_vector_type(4))) float g4_f32x4;

__device__ __forceinline__ float g4_bf2f(unsigned short h) {
    union { unsigned int u; float f; } v;
    v.u = ((unsigned int)h) << 16;
    return v.f;
}
__device__ __forceinline__ unsigned short g4_f2bf(float f) {
    union { float f; unsigned int u; } v;
    v.f = f;
    unsigned int u = v.u;
    u += 0x7fffu + ((u >> 16) & 1u);   // RNE
    return (unsigned short)(u >> 16);
}
__device__ __forceinline__ float g4_ld(const void* p, size_t i, int isf) {
    return isf ? ((const float*)p)[i] : g4_bf2f(((const unsigned short*)p)[i]);
}

// ---------------------------------------------------------------------------
// init: dtype detect (block 0) + zero deg/cnt + d_out sentinel
// ---------------------------------------------------------------------------
__global__ void g4_init(const unsigned int* __restrict__ xw,
                        const int* __restrict__ ei32, int* __restrict__ flags,
                        int* __restrict__ deg, int* __restrict__ cnt,
                        unsigned int* __restrict__ outw) {
    if (blockIdx.x == 0) {
        __shared__ int cs[256];
        int t = threadIdx.x;
        unsigned int w = xw[t];
        int e = (int)((w >> 23) & 0xffu);
        cs[t] = (e >= 110 && e <= 135) ? 1 : 0;
        __syncthreads();
        for (int off = 128; off > 0; off >>= 1) {
            if (t < off) cs[t] += cs[t + off];
            __syncthreads();
        }
        if (t == 0) {
            flags[0] = (cs[0] >= 128) ? 1 : 0;
            int i64 = (ei32[1] == 0 && ei32[3] == 0 && ei32[5] == 0 &&
                       ei32[7] == 0 && ei32[9] == 0) ? 1 : 0;
            flags[1] = i64;
        }
    }
    int i = blockIdx.x * 256 + threadIdx.x;
    if (i < NN) { deg[i] = 0; cnt[i] = 0; }
    if (i < SENT_WORDS) outw[i] = SENT_VAL;
}

// ---------------------------------------------------------------------------
// CSR build
// ---------------------------------------------------------------------------
__global__ void g4_hist(const int* __restrict__ ei, const int* __restrict__ flags,
                        int* __restrict__ deg) {
    int e = blockIdx.x * blockDim.x + threadIdx.x;
    if (e >= ETOT) return;
    int i64 = flags[1];
    int d;
    if (e < EE) d = i64 ? ei[2 * (EE + e)] : ei[EE + e];
    else        d = e - EE;
    atomicAdd(&deg[d], 1);
}

__global__ void g4_scan_block(const int* __restrict__ deg, int* __restrict__ tmp,
                              int* __restrict__ partial) {
    __shared__ int sh[256];
    int i = blockIdx.x * 256 + threadIdx.x;
    int v = (i < NN) ? deg[i] : 0;
    sh[threadIdx.x] = v;
    __syncthreads();
    for (int off = 1; off < 256; off <<= 1) {
        int t = (threadIdx.x >= off) ? sh[threadIdx.x - off] : 0;
        __syncthreads();
        sh[threadIdx.x] += t;
        __syncthreads();
    }
    if (i < NN) tmp[i] = sh[threadIdx.x] - v;
    if (threadIdx.x == 255) partial[blockIdx.x] = sh[255];
}

__global__ void g4_scan_partial(int* __restrict__ partial, int nb,
                                int* __restrict__ rowptrN) {
    __shared__ int sh[256];
    int v = (threadIdx.x < nb) ? partial[threadIdx.x] : 0;
    sh[threadIdx.x] = v;
    __syncthreads();
    for (int off = 1; off < 256; off <<= 1) {
        int t = (threadIdx.x >= off) ? sh[threadIdx.x - off] : 0;
        __syncthreads();
        sh[threadIdx.x] += t;
        __syncthreads();
    }
    if (threadIdx.x < nb) partial[threadIdx.x] = sh[threadIdx.x] - v;
    if (threadIdx.x == 0) *rowptrN = ETOT;
}

__global__ void g4_scan_add(const int* __restrict__ tmp, const int* __restrict__ partial,
                            int* __restrict__ rowptr) {
    int i = blockIdx.x * 256 + threadIdx.x;
    if (i < NN) rowptr[i] = tmp[i] + partial[blockIdx.x];
}

__global__ void g4_fill_csr(const int* __restrict__ ei, const int* __restrict__ flags,
                            const int* __restrict__ rowptr,
                            int* __restrict__ cnt, int* __restrict__ col) {
    int e = blockIdx.x * blockDim.x + threadIdx.x;
    if (e >= ETOT) return;
    int i64 = flags[1];
    int s, d;
    if (e < EE) {
        s = i64 ? ei[2 * e] : ei[e];
        d = i64 ? ei[2 * (EE + e)] : ei[EE + e];
    } else {
        s = e - EE; d = e - EE;
    }
    int pos = rowptr[d] + atomicAdd(&cnt[d], 1);
    col[pos] = s;
}

// ---------------------------------------------------------------------------
// Layer-0 A pad: Apad[NN][64] (bf16) from x[NN][61] (dtype per flags).
// ---------------------------------------------------------------------------
__global__ void g4_aprep(const void* __restrict__ x, const int* __restrict__ flags,
                         unsigned short* __restrict__ Apad) {
    int i = blockIdx.x * 256 + threadIdx.x;
    if (i >= NN * 64) return;
    int row = i >> 6, k = i & 63;
    unsigned short v = 0;
    if (k < 61) {
        if (flags[0]) v = g4_f2bf(((const float*)x)[(size_t)row * 61 + k]);
        else          v = ((const unsigned short*)x)[(size_t)row * 61 + k];
    }
    Apad[i] = v;
}

// ---------------------------------------------------------------------------
// Weight prep in FRAGMENT order: frag index f=0..15 covers cols f*16+(lane&15),
// Bfrag[((f*NK+ks)*64+lane)*8 + j] = B[k][n], k = ks*32+(lane>>4)*8+j.
// ---------------------------------------------------------------------------
__global__ void g4_bfprep(const void* __restrict__ B, const int* __restrict__ flags,
                          unsigned short* __restrict__ Bfrag, int K, int NK) {
    int i = blockIdx.x * 256 + threadIdx.x;
    if (i >= HC * NK * 32) return;
    int j = i & 7;
    int rest = i >> 3;
    int lane = rest & 63; rest >>= 6;
    int ks = rest % NK;
    int f  = rest / NK;                 // 0..15
    int n = f * 16 + (lane & 15);
    int k = ks * 32 + (lane >> 4) * 8 + j;
    unsigned short v = 0;
    if (k < K) {
        if (flags[0]) v = g4_f2bf(((const float*)B)[(size_t)k * HC + n]);
        else          v = ((const unsigned short*)B)[(size_t)k * HC + n];
    }
    Bfrag[i] = v;
}

// ---------------------------------------------------------------------------
// MFMA GEMM + fused logits. No LDS, no barriers.
// NEW mapping: each wave owns 16 rows x ALL 256 cols (16 acc frags).
// -> each A row is read by exactly ONE wave (no L1-thrashing redundancy);
//    per k-step: 1 A-load + 16 independent L2-hot B-loads + 16 MFMA.
// ---------------------------------------------------------------------------
template <int NK>
__global__ __launch_bounds__(256) void g4_gemm3(
    const unsigned short* __restrict__ A, const unsigned short* __restrict__ Bfrag,
    const int* __restrict__ flags, unsigned short* __restrict__ C,
    const void* __restrict__ att_src, const void* __restrict__ att_dst,
    float* __restrict__ a_srcO, float* __restrict__ a_dstO, int M) {
    const int KP   = NK * 32;
    const int isf  = flags[0];
    const int tid  = threadIdx.x;
    const int lane = tid & 63;
    const int wq   = tid >> 6;       // wave -> 16-row slice
    const int quad = lane >> 4;
    const int l15  = lane & 15;
    const int bm   = blockIdx.x * 64 + wq * 16;

    g4_f32x4 acc[16];
    #pragma unroll
    for (int jt = 0; jt < 16; jt++) {
        acc[jt].x = 0.f; acc[jt].y = 0.f; acc[jt].z = 0.f; acc[jt].w = 0.f;
    }

    #pragma unroll
    for (int ks = 0; ks < NK; ks++) {
        g4_bf16x8 afr = *(const g4_bf16x8*)
            (A + (size_t)(bm + l15) * KP + ks * 32 + quad * 8);
        #pragma unroll
        for (int jt = 0; jt < 16; jt++) {
            g4_bf16x8 bfr = *(const g4_bf16x8*)
                (Bfrag + ((size_t)((jt * NK + ks) * 64 + lane) << 3));
            acc[jt] = __builtin_amdgcn_mfma_f32_16x16x32_bf16(afr, bfr, acc[jt], 0, 0, 0);
        }
    }

    // ---- C store: D col = l15 (within frag jt), row = quad*4 + r
    #pragma unroll
    for (int jt = 0; jt < 16; jt++) {
        #pragma unroll
        for (int r = 0; r < 4; r++) {
            int gm = bm + quad * 4 + r;
            if (gm < M) C[(size_t)gm * HC + jt * 16 + l15] = g4_f2bf(acc[jt][r]);
        }
    }

    // ---- fused logits: per row, per head, dot over that head's 64 cols
    float asv[16], adv[16];
    #pragma unroll
    for (int jt = 0; jt < 16; jt++) {
        asv[jt] = g4_ld(att_src, jt * 16 + l15, isf);
        adv[jt] = g4_ld(att_dst, jt * 16 + l15, isf);
    }
    #pragma unroll
    for (int r = 0; r < 4; r++) {
        float ps[4] = {0.f, 0.f, 0.f, 0.f};
        float pd[4] = {0.f, 0.f, 0.f, 0.f};
        #pragma unroll
        for (int jt = 0; jt < 16; jt++) {
            ps[jt >> 2] += acc[jt][r] * asv[jt];
            pd[jt >> 2] += acc[jt][r] * adv[jt];
        }
        #pragma unroll
        for (int off = 1; off < 16; off <<= 1)
            #pragma unroll
            for (int hh = 0; hh < 4; hh++) {
                ps[hh] += __shfl_xor(ps[hh], off);
                pd[hh] += __shfl_xor(pd[hh], off);
            }
        if (l15 == 0) {
            int gm = bm + quad * 4 + r;
            if (gm < M) {
                #pragma unroll
                for (int hh = 0; hh < 4; hh++) {
                    a_srcO[gm * 4 + hh] = ps[hh];
                    a_dstO[gm * 4 + hh] = pd[hh];
                }
            }
        }
    }
}

// ---------------------------------------------------------------------------
// Fused softmax+gather (4-wide pipelined h-loads). Wave per dst.
// ---------------------------------------------------------------------------
__global__ __launch_bounds__(256) void g4_gatherf(
    const unsigned short* __restrict__ h,
    const float* __restrict__ a_src, const float* __restrict__ a_dst,
    const int* __restrict__ rowptr, const int* __restrict__ col,
    const void* __restrict__ bias, const int* __restrict__ flags,
    unsigned short* __restrict__ xout) {
    int d    = (blockIdx.x * blockDim.x + threadIdx.x) >> 6;
    int lane = threadIdx.x & 63;
    if (d >= NN) return;
    d = __builtin_amdgcn_readfirstlane(d);
    const int isf = flags[0];
    const int hd  = lane >> 4;        // head for channel role
    const int q   = lane & 3;         // head for exp role
    const int eloc = lane >> 2;       // edge slot for exp role (0..15)
    const int l15 = lane & 15;
    const int start = __builtin_amdgcn_readfirstlane(rowptr[d]);
    const int end   = __builtin_amdgcn_readfirstlane(rowptr[d + 1]);

    // phase 1: per-head max of leaky-relu logits
    g4_f32x4 ad4 = *(const g4_f32x4*)(a_dst + 4 * (size_t)d);
    float mx[4] = {-1e30f, -1e30f, -1e30f, -1e30f};
    for (int i = start + lane; i < end; i += 64) {
        int s = col[i];
        g4_f32x4 as = *(const g4_f32x4*)(a_src + 4 * (size_t)s);
        #pragma unroll
        for (int hh = 0; hh < 4; hh++) {
            float e = as[hh] + ad4[hh];
            e = (e > 0.f) ? e : NEG_SLOPE * e;
            mx[hh] = fmaxf(mx[hh], e);
        }
    }
    for (int off = 32; off > 0; off >>= 1)
        #pragma unroll
        for (int hh = 0; hh < 4; hh++) mx[hh] = fmaxf(mx[hh], __shfl_xor(mx[hh], off));
    float mxq = (q < 2) ? ((q == 0) ? mx[0] : mx[1]) : ((q == 2) ? mx[2] : mx[3]);
    float adq = (q < 2) ? ((q == 0) ? ad4.x : ad4.y) : ((q == 2) ? ad4.z : ad4.w);

    // phase 2: gather + inline exp + denom
    float a0 = 0.f, a1 = 0.f, a2 = 0.f, a3 = 0.f;
    float sm = 0.f;
    const size_t ch = (size_t)(lane << 2);
    for (int base = start; base < end; base += 16) {
        int m = end - base;
        if (m > 16) m = 16;
        int cv = col[base + l15];
        int sE = __shfl(cv, eloc);
        float av = 0.f;
        if (eloc < m) {
            float e = a_src[4 * (size_t)sE + q] + adq;
            e = (e > 0.f) ? e : NEG_SLOPE * e;
            av = __expf(e - mxq);
            sm += av;
        }
        int j = 0;
        for (; j + 4 <= m; j += 4) {
            int s0 = __shfl(cv, j);
            int s1 = __shfl(cv, j + 1);
            int s2 = __shfl(cv, j + 2);
            int s3 = __shfl(cv, j + 3);
            float w0 = __shfl(av, 4 * j + hd);
            float w1 = __shfl(av, 4 * j + 4 + hd);
            float w2 = __shfl(av, 4 * j + 8 + hd);
            float w3 = __shfl(av, 4 * j + 12 + hd);
            uint2 h0 = *(const uint2*)(h + (((size_t)s0) << 8) + ch);
            uint2 h1 = *(const uint2*)(h + (((size_t)s1) << 8) + ch);
            uint2 h2 = *(const uint2*)(h + (((size_t)s2) << 8) + ch);
            uint2 h3 = *(const uint2*)(h + (((size_t)s3) << 8) + ch);
            a0 = fmaf(__uint_as_float(h0.x << 16),         w0, a0);
            a1 = fmaf(__uint_as_float(h0.x & 0xffff0000u), w0, a1);
            a2 = fmaf(__uint_as_float(h0.y << 16),         w0, a2);
            a3 = fmaf(__uint_as_float(h0.y & 0xffff0000u), w0, a3);
            a0 = fmaf(__uint_as_float(h1.x << 16),         w1, a0);
            a1 = fmaf(__uint_as_float(h1.x & 0xffff0000u), w1, a1);
            a2 = fmaf(__uint_as_float(h1.y << 16),         w1, a2);
            a3 = fmaf(__uint_as_float(h1.y & 0xffff0000u), w1, a3);
            a0 = fmaf(__uint_as_float(h2.x << 16),         w2, a0);
            a1 = fmaf(__uint_as_float(h2.x & 0xffff0000u), w2, a1);
            a2 = fmaf(__uint_as_float(h2.y << 16),         w2, a2);
            a3 = fmaf(__uint_as_float(h2.y & 0xffff0000u), w2, a3);
            a0 = fmaf(__uint_as_float(h3.x << 16),         w3, a0);
            a1 = fmaf(__uint_as_float(h3.x & 0xffff0000u), w3, a1);
            a2 = fmaf(__uint_as_float(h3.y << 16),         w3, a2);
            a3 = fmaf(__uint_as_float(h3.y & 0xffff0000u), w3, a3);
        }
        for (; j < m; j++) {
            int s = __shfl(cv, j);
            float w = __shfl(av, 4 * j + hd);
            uint2 hv = *(const uint2*)(h + (((size_t)s) << 8) + ch);
            a0 = fmaf(__uint_as_float(hv.x << 16),         w, a0);
            a1 = fmaf(__uint_as_float(hv.x & 0xffff0000u), w, a1);
            a2 = fmaf(__uint_as_float(hv.y << 16),         w, a2);
            a3 = fmaf(__uint_as_float(hv.y & 0xffff0000u), w, a3);
        }
    }
    for (int off = 4; off < 64; off <<= 1) sm += __shfl_xor(sm, off);
    float inv = 1.f / __shfl(sm, hd);
    float acc[4] = {a0 * inv, a1 * inv, a2 * inv, a3 * inv};
    unsigned short ov[4];
    #pragma unroll
    for (int j = 0; j < 4; j++) {
        float v = acc[j] + g4_ld(bias, (lane << 2) + j, isf);
        v = (v > 0.f) ? v : (__expf(v) - 1.f);
        ov[j] = g4_f2bf(v);
    }
    uint2 pack;
    pack.x = (unsigned int)ov[0] | ((unsigned int)ov[1] << 16);
    pack.y = (unsigned int)ov[2] | ((unsigned int)ov[3] << 16);
    *(uint2*)(xout + ((size_t)d << 8) + (lane << 2)) = pack;
}

// ---------------------------------------------------------------------------
// Fused MLP head
// ---------------------------------------------------------------------------
__global__ __launch_bounds__(256) void g4_head2(
    const unsigned short* __restrict__ x, const void* __restrict__ w1,
    const void* __restrict__ b1, const void* __restrict__ w2,
    const void* __restrict__ b2, const int* __restrict__ flags,
    void* __restrict__ outp) {
    __shared__ float As[64][17];
    __shared__ float Bs[16][64];
    __shared__ float red[64][17];
    const int isf = flags[0];
    const int tid = threadIdx.x;
    const int bm  = blockIdx.x * 64;
    const int tx  = tid & 15;
    const int ty  = tid >> 4;
    float acc[4][4] = {};
    for (int k0 = 0; k0 < HC; k0 += 16) {
        for (int i = tid; i < 64 * 16; i += 256) {
            int m = i >> 4, kk = i & 15;
            int gm = bm + m;
            float v = 0.f;
            if (gm < NN) v = g4_bf2f(x[(size_t)gm * HC + k0 + kk]);
            As[m][kk] = v;
        }
        for (int i = tid; i < 16 * 64; i += 256) {
            int kk = i >> 6, n = i & 63;
            Bs[kk][n] = g4_ld(w1, (size_t)(k0 + kk) * 64 + n, isf);
        }
        __syncthreads();
        #pragma unroll
        for (int kk = 0; kk < 16; ++kk) {
            float a[4], b[4];
            #pragma unroll
            for (int i = 0; i < 4; i++) a[i] = As[ty * 4 + i][kk];
            #pragma unroll
            for (int j = 0; j < 4; j++) b[j] = Bs[kk][tx * 4 + j];
            #pragma unroll
            for (int i = 0; i < 4; i++)
                #pragma unroll
                for (int j = 0; j < 4; j++) acc[i][j] += a[i] * b[j];
        }
        __syncthreads();
    }
    float b1v[4], w2v[4];
    #pragma unroll
    for (int j = 0; j < 4; j++) {
        b1v[j] = g4_ld(b1, tx * 4 + j, isf);
        w2v[j] = g4_ld(w2, tx * 4 + j, isf);
    }
    #pragma unroll
    for (int i = 0; i < 4; i++) {
        float s = 0.f;
        #pragma unroll
        for (int j = 0; j < 4; j++) {
            float v = acc[i][j] + b1v[j];
            v = fmaxf(v, 0.f);
            s += v * w2v[j];
        }
        red[ty * 4 + i][tx] = s;
    }
    __syncthreads();
    if (tid < 64) {
        float s = 0.f;
        #pragma unroll
        for (int g = 0; g < 16; g++) s += red[tid][g];
        int gm = bm + tid;
        if (gm < NN) {
            float r = s + g4_ld(b2, 0, isf);
            if (isf) ((float*)outp)[gm] = r;
            else     ((unsigned short*)outp)[gm] = g4_f2bf(r);
        }
    }
}

// ---------------------------------------------------------------------------
extern "C" __attribute__((visibility("default")))
void kernel_launch(void* const* d_in, const int* in_sizes, int n_in,
                   void* d_out, int out_size, void* d_ws, size_t ws_size,
                   hipStream_t stream) {
    const void* x_in = d_in[0];
    const int*  ei   = (const int*)d_in[1];
    const void* W[3]    = {d_in[2], d_in[6], d_in[10]};
    const void* ASRC[3] = {d_in[3], d_in[7], d_in[11]};
    const void* ADST[3] = {d_in[4], d_in[8], d_in[12]};
    const void* BIAS[3] = {d_in[5], d_in[9], d_in[13]};
    const void* hw1 = d_in[14];
    const void* hb1 = d_in[15];
    const void* hw2 = d_in[16];
    const void* hb2 = d_in[17];

    char* base = (char*)d_ws;
    size_t woff = 0;
#define G4_TAKE(name, type, count) \
    type* name = (type*)(base + woff); \
    woff += (((size_t)(count)) * sizeof(type) + 255) & ~(size_t)255;
    G4_TAKE(flags,   int, 8)
    G4_TAKE(deg,     int, NN)
    G4_TAKE(cnt,     int, NN)
    G4_TAKE(tmp,     int, NN)
    G4_TAKE(partial, int, 256)
    G4_TAKE(rowptr,  int, NN + 1)
    G4_TAKE(col,     int, ETOT + 16)
    G4_TAKE(asr,     float, (size_t)NN * 4)
    G4_TAKE(adsb,    float, (size_t)NN * 4)
    G4_TAKE(Apad,    unsigned short, (size_t)(NN + 64) * 64)
    G4_TAKE(Bfrag,   unsigned short, (size_t)HC * HC)
    G4_TAKE(hbuf,    unsigned short, (size_t)(NN + 64) * HC)
    G4_TAKE(xbuf,    unsigned short, (size_t)(NN + 64) * HC)
#undef G4_TAKE

    const int SCAN_BLOCKS = (NN + 255) / 256;          // 196
    const int EDGE_BLOCKS = (ETOT + 255) / 256;        // 3321
    const int WAVE_BLOCKS = (NN + 3) / 4;              // 12500
    const int TILE_BLOCKS = (NN + 63) / 64;            // 782

    g4_init<<<SCAN_BLOCKS, 256, 0, stream>>>((const unsigned int*)x_in, ei, flags,
                                             deg, cnt, (unsigned int*)d_out);

    g4_hist<<<EDGE_BLOCKS, 256, 0, stream>>>(ei, flags, deg);
    g4_scan_block<<<SCAN_BLOCKS, 256, 0, stream>>>(deg, tmp, partial);
    g4_scan_partial<<<1, 256, 0, stream>>>(partial, SCAN_BLOCKS, rowptr + NN);
    g4_scan_add<<<SCAN_BLOCKS, 256, 0, stream>>>(tmp, partial, rowptr);
    g4_fill_csr<<<EDGE_BLOCKS, 256, 0, stream>>>(ei, flags, rowptr, cnt, col);

    // layer-0 A padding to K=64
    g4_aprep<<<(NN * 64 + 255) / 256, 256, 0, stream>>>(x_in, flags, Apad);

    for (int l = 0; l < 3; l++) {
        int K  = (l == 0) ? 61 : HC;
        int NK = (l == 0) ? 2  : 8;
        g4_bfprep<<<(HC * NK * 32 + 255) / 256, 256, 0, stream>>>(W[l], flags, Bfrag, K, NK);
        if (l == 0) {
            g4_gemm3<2><<<TILE_BLOCKS, 256, 0, stream>>>(Apad, Bfrag, flags, hbuf,
                ASRC[l], ADST[l], asr, adsb, NN);
        } else {
            g4_gemm3<8><<<TILE_BLOCKS, 256, 0, stream>>>(xbuf, Bfrag, flags, hbuf,
                ASRC[l], ADST[l], asr, adsb, NN);
        }
        g4_gatherf<<<WAVE_BLOCKS, 256, 0, stream>>>(hbuf, asr, adsb, rowptr, col,
                                                    BIAS[l], flags, xbuf);
    }
    g4_head2<<<TILE_BLOCKS, 256, 0, stream>>>(xbuf, hw1, hb1, hw2, hb2, flags, d_out);
}

// Round 16
// 526.045 us; speedup vs baseline: 1.1605x; 1.1605x over previous
//
#include <hip/hip_runtime.h>
#include <cstdint>
#include <cstddef>

#define NN   50000
#define EE   800000
#define ETOT (EE + NN)
#define HC   256
#define NEG_SLOPE 0.2f
#define SENT_WORDS 25000
#define SENT_VAL 0x42C80000u

typedef __attribute__((ext_vector_type(8))) short g4_bf16x8;
typedef __attribute__((ext_vector_type(4))) float g4_f32x4;

__device__ __forceinline__ float g4_bf2f(unsigned short h) {
    union { unsigned int u; float f; } v;
    v.u = ((unsigned int)h) << 16;
    return v.f;
}
__device__ __forceinline__ unsigned short g4_f2bf(float f) {
    union { float f; unsigned int u; } v;
    v.f = f;
    unsigned int u = v.u;
    u += 0x7fffu + ((u >> 16) & 1u);   // RNE
    return (unsigned short)(u >> 16);
}
__device__ __forceinline__ float g4_ld(const void* p, size_t i, int isf) {
    return isf ? ((const float*)p)[i] : g4_bf2f(((const unsigned short*)p)[i]);
}

// ---------------------------------------------------------------------------
// init: dtype detect (block 0) + zero deg/cnt + d_out sentinel
// ---------------------------------------------------------------------------
__global__ void g4_init(const unsigned int* __restrict__ xw,
                        const int* __restrict__ ei32, int* __restrict__ flags,
                        int* __restrict__ deg, int* __restrict__ cnt,
                        unsigned int* __restrict__ outw) {
    if (blockIdx.x == 0) {
        __shared__ int cs[256];
        int t = threadIdx.x;
        unsigned int w = xw[t];
        int e = (int)((w >> 23) & 0xffu);
        cs[t] = (e >= 110 && e <= 135) ? 1 : 0;
        __syncthreads();
        for (int off = 128; off > 0; off >>= 1) {
            if (t < off) cs[t] += cs[t + off];
            __syncthreads();
        }
        if (t == 0) {
            flags[0] = (cs[0] >= 128) ? 1 : 0;
            int i64 = (ei32[1] == 0 && ei32[3] == 0 && ei32[5] == 0 &&
                       ei32[7] == 0 && ei32[9] == 0) ? 1 : 0;
            flags[1] = i64;
        }
    }
    int i = blockIdx.x * 256 + threadIdx.x;
    if (i < NN) { deg[i] = 0; cnt[i] = 0; }
    if (i < SENT_WORDS) outw[i] = SENT_VAL;
}

// ---------------------------------------------------------------------------
// CSR build
// ---------------------------------------------------------------------------
__global__ void g4_hist(const int* __restrict__ ei, const int* __restrict__ flags,
                        int* __restrict__ deg) {
    int e = blockIdx.x * blockDim.x + threadIdx.x;
    if (e >= ETOT) return;
    int i64 = flags[1];
    int d;
    if (e < EE) d = i64 ? ei[2 * (EE + e)] : ei[EE + e];
    else        d = e - EE;
    atomicAdd(&deg[d], 1);
}

__global__ void g4_scan_block(const int* __restrict__ deg, int* __restrict__ tmp,
                              int* __restrict__ partial) {
    __shared__ int sh[256];
    int i = blockIdx.x * 256 + threadIdx.x;
    int v = (i < NN) ? deg[i] : 0;
    sh[threadIdx.x] = v;
    __syncthreads();
    for (int off = 1; off < 256; off <<= 1) {
        int t = (threadIdx.x >= off) ? sh[threadIdx.x - off] : 0;
        __syncthreads();
        sh[threadIdx.x] += t;
        __syncthreads();
    }
    if (i < NN) tmp[i] = sh[threadIdx.x] - v;
    if (threadIdx.x == 255) partial[blockIdx.x] = sh[255];
}

__global__ void g4_scan_partial(int* __restrict__ partial, int nb,
                                int* __restrict__ rowptrN) {
    __shared__ int sh[256];
    int v = (threadIdx.x < nb) ? partial[threadIdx.x] : 0;
    sh[threadIdx.x] = v;
    __syncthreads();
    for (int off = 1; off < 256; off <<= 1) {
        int t = (threadIdx.x >= off) ? sh[threadIdx.x - off] : 0;
        __syncthreads();
        sh[threadIdx.x] += t;
        __syncthreads();
    }
    if (threadIdx.x < nb) partial[threadIdx.x] = sh[threadIdx.x] - v;
    if (threadIdx.x == 0) *rowptrN = ETOT;
}

__global__ void g4_scan_add(const int* __restrict__ tmp, const int* __restrict__ partial,
                            int* __restrict__ rowptr) {
    int i = blockIdx.x * 256 + threadIdx.x;
    if (i < NN) rowptr[i] = tmp[i] + partial[blockIdx.x];
}

__global__ void g4_fill_csr(const int* __restrict__ ei, const int* __restrict__ flags,
                            const int* __restrict__ rowptr,
                            int* __restrict__ cnt, int* __restrict__ col) {
    int e = blockIdx.x * blockDim.x + threadIdx.x;
    if (e >= ETOT) return;
    int i64 = flags[1];
    int s, d;
    if (e < EE) {
        s = i64 ? ei[2 * e] : ei[e];
        d = i64 ? ei[2 * (EE + e)] : ei[EE + e];
    } else {
        s = e - EE; d = e - EE;
    }
    int pos = rowptr[d] + atomicAdd(&cnt[d], 1);
    col[pos] = s;
}

// ---------------------------------------------------------------------------
// Layer-0 A pad: Apad[NN][64] (bf16) from x[NN][61] (dtype per flags).
// ---------------------------------------------------------------------------
__global__ void g4_aprep(const void* __restrict__ x, const int* __restrict__ flags,
                         unsigned short* __restrict__ Apad) {
    int i = blockIdx.x * 256 + threadIdx.x;
    if (i >= NN * 64) return;
    int row = i >> 6, k = i & 63;
    unsigned short v = 0;
    if (k < 61) {
        if (flags[0]) v = g4_f2bf(((const float*)x)[(size_t)row * 61 + k]);
        else          v = ((const unsigned short*)x)[(size_t)row * 61 + k];
    }
    Apad[i] = v;
}

// ---------------------------------------------------------------------------
// Weight prep in per-wave FRAGMENT order:
// Bfrag[(((wc*4+jt)*NK+ks)*64+lane)*8 + j] = B[k][n],
//   n = wc*64+jt*16+(lane&15), k = ks*32+(lane>>4)*8+j  (0 if k>=K).
// ---------------------------------------------------------------------------
__global__ void g4_bfprep(const void* __restrict__ B, const int* __restrict__ flags,
                          unsigned short* __restrict__ Bfrag, int K, int NK) {
    int i = blockIdx.x * 256 + threadIdx.x;
    if (i >= HC * NK * 32) return;
    int j = i & 7;
    int rest = i >> 3;
    int lane = rest & 63; rest >>= 6;
    int ks = rest % NK;
    int wcjt = rest / NK;
    int jt = wcjt & 3, wc = wcjt >> 2;
    int n = wc * 64 + jt * 16 + (lane & 15);
    int k = ks * 32 + (lane >> 4) * 8 + j;
    unsigned short v = 0;
    if (k < K) {
        if (flags[0]) v = g4_f2bf(((const float*)B)[(size_t)k * HC + n]);
        else          v = ((const unsigned short*)B)[(size_t)k * HC + n];
    }
    Bfrag[i] = v;
}

// ---------------------------------------------------------------------------
// MFMA GEMM + fused logits. No barriers in the K-loop; B frags from L2.
// R16: explicit 2-stage register pipeline — stage k+1's 8 frag loads issue
// before the 16 MFMAs consuming stage k (latency hiding at low occupancy).
// C-store via wave-private LDS for coalesced dwordx2 stores.
// ---------------------------------------------------------------------------
template <int NK>
__global__ __launch_bounds__(256) void g4_gemm3(
    const unsigned short* __restrict__ A, const unsigned short* __restrict__ Bfrag,
    const int* __restrict__ flags, unsigned short* __restrict__ C,
    const void* __restrict__ att_src, const void* __restrict__ att_dst,
    float* __restrict__ a_srcO, float* __restrict__ a_dstO, int M) {
    __shared__ unsigned short wsep[4 * 64 * 72];   // 36 KB: 4 waves x 64x64(+8 pad)
    const int KP   = NK * 32;
    const int isf  = flags[0];
    const int tid  = threadIdx.x;
    const int lane = tid & 63;
    const int wc   = tid >> 6;       // wave = head
    const int quad = lane >> 4;
    const int l15  = lane & 15;
    const int bm   = blockIdx.x * 64;

    g4_f32x4 acc[4][4];
    #pragma unroll
    for (int it = 0; it < 4; it++)
        #pragma unroll
        for (int jt = 0; jt < 4; jt++) {
            acc[it][jt].x = 0.f; acc[it][jt].y = 0.f;
            acc[it][jt].z = 0.f; acc[it][jt].w = 0.f;
        }

    const unsigned short* Abase = A + (size_t)(bm + l15) * KP + quad * 8;
    const unsigned short* Bbase = Bfrag + ((size_t)(wc * 4 * NK * 64 + lane) << 3);

    g4_bf16x8 af0[4], bf0[4], af1[4], bf1[4];
    #pragma unroll
    for (int it = 0; it < 4; it++)
        af0[it] = *(const g4_bf16x8*)(Abase + (size_t)it * 16 * KP);
    #pragma unroll
    for (int jt = 0; jt < 4; jt++)
        bf0[jt] = *(const g4_bf16x8*)(Bbase + (((size_t)jt * NK) * 64 << 3));

    #pragma unroll
    for (int ks = 0; ks < NK; ks++) {
        if ((ks & 1) == 0) {
            if (ks + 1 < NK) {
                #pragma unroll
                for (int it = 0; it < 4; it++)
                    af1[it] = *(const g4_bf16x8*)(Abase + (size_t)it * 16 * KP + (ks + 1) * 32);
                #pragma unroll
                for (int jt = 0; jt < 4; jt++)
                    bf1[jt] = *(const g4_bf16x8*)(Bbase + (((size_t)(jt * NK + ks + 1)) * 64 << 3));
            }
            #pragma unroll
            for (int it = 0; it < 4; it++)
                #pragma unroll
                for (int jt = 0; jt < 4; jt++)
                    acc[it][jt] = __builtin_amdgcn_mfma_f32_16x16x32_bf16(
                        af0[it], bf0[jt], acc[it][jt], 0, 0, 0);
        } else {
            if (ks + 1 < NK) {
                #pragma unroll
                for (int it = 0; it < 4; it++)
                    af0[it] = *(const g4_bf16x8*)(Abase + (size_t)it * 16 * KP + (ks + 1) * 32);
                #pragma unroll
                for (int jt = 0; jt < 4; jt++)
                    bf0[jt] = *(const g4_bf16x8*)(Bbase + (((size_t)(jt * NK + ks + 1)) * 64 << 3));
            }
            #pragma unroll
            for (int it = 0; it < 4; it++)
                #pragma unroll
                for (int jt = 0; jt < 4; jt++)
                    acc[it][jt] = __builtin_amdgcn_mfma_f32_16x16x32_bf16(
                        af1[it], bf1[jt], acc[it][jt], 0, 0, 0);
        }
    }

    // ---- C store through wave-private LDS, coalesced dwordx2 out
    {
        unsigned short* w = &wsep[wc * (64 * 72)];
        #pragma unroll
        for (int it = 0; it < 4; it++)
            #pragma unroll
            for (int jt = 0; jt < 4; jt++)
                #pragma unroll
                for (int r = 0; r < 4; r++)
                    w[(it * 16 + quad * 4 + r) * 72 + jt * 16 + l15] =
                        g4_f2bf(acc[it][jt][r]);
        // wave-private region: in-wave DS ordering suffices, no barrier
        #pragma unroll
        for (int rr = 0; rr < 16; rr++) {
            int row = rr * 4 + quad;
            uint2 v = *(const uint2*)&w[row * 72 + l15 * 4];
            int gm = bm + row;
            if (gm < M)
                *(uint2*)(C + (size_t)gm * HC + wc * 64 + l15 * 4) = v;
        }
    }
    // ---- fused logits
    float asv[4], adv[4];
    #pragma unroll
    for (int jt = 0; jt < 4; jt++) {
        asv[jt] = g4_ld(att_src, wc * 64 + jt * 16 + l15, isf);
        adv[jt] = g4_ld(att_dst, wc * 64 + jt * 16 + l15, isf);
    }
    #pragma unroll
    for (int it = 0; it < 4; it++) {
        #pragma unroll
        for (int r = 0; r < 4; r++) {
            float ps = 0.f, pd = 0.f;
            #pragma unroll
            for (int jt = 0; jt < 4; jt++) {
                ps += acc[it][jt][r] * asv[jt];
                pd += acc[it][jt][r] * adv[jt];
            }
            #pragma unroll
            for (int off = 1; off < 16; off <<= 1) {
                ps += __shfl_xor(ps, off);
                pd += __shfl_xor(pd, off);
            }
            if (l15 == 0) {
                int gm = bm + it * 16 + quad * 4 + r;
                if (gm < M) {
                    a_srcO[gm * 4 + wc] = ps;
                    a_dstO[gm * 4 + wc] = pd;
                }
            }
        }
    }
}

// ---------------------------------------------------------------------------
// Fused softmax+gather (4-wide pipelined h-loads). Wave per dst.
// ---------------------------------------------------------------------------
__global__ __launch_bounds__(256) void g4_gatherf(
    const unsigned short* __restrict__ h,
    const float* __restrict__ a_src, const float* __restrict__ a_dst,
    const int* __restrict__ rowptr, const int* __restrict__ col,
    const void* __restrict__ bias, const int* __restrict__ flags,
    unsigned short* __restrict__ xout) {
    int d    = (blockIdx.x * blockDim.x + threadIdx.x) >> 6;
    int lane = threadIdx.x & 63;
    if (d >= NN) return;
    d = __builtin_amdgcn_readfirstlane(d);
    const int isf = flags[0];
    const int hd  = lane >> 4;        // head for channel role
    const int q   = lane & 3;         // head for exp role
    const int eloc = lane >> 2;       // edge slot for exp role (0..15)
    const int l15 = lane & 15;
    const int start = __builtin_amdgcn_readfirstlane(rowptr[d]);
    const int end   = __builtin_amdgcn_readfirstlane(rowptr[d + 1]);

    // phase 1: per-head max of leaky-relu logits
    g4_f32x4 ad4 = *(const g4_f32x4*)(a_dst + 4 * (size_t)d);
    float mx[4] = {-1e30f, -1e30f, -1e30f, -1e30f};
    for (int i = start + lane; i < end; i += 64) {
        int s = col[i];
        g4_f32x4 as = *(const g4_f32x4*)(a_src + 4 * (size_t)s);
        #pragma unroll
        for (int hh = 0; hh < 4; hh++) {
            float e = as[hh] + ad4[hh];
            e = (e > 0.f) ? e : NEG_SLOPE * e;
            mx[hh] = fmaxf(mx[hh], e);
        }
    }
    for (int off = 32; off > 0; off >>= 1)
        #pragma unroll
        for (int hh = 0; hh < 4; hh++) mx[hh] = fmaxf(mx[hh], __shfl_xor(mx[hh], off));
    float mxq = (q < 2) ? ((q == 0) ? mx[0] : mx[1]) : ((q == 2) ? mx[2] : mx[3]);
    float adq = (q < 2) ? ((q == 0) ? ad4.x : ad4.y) : ((q == 2) ? ad4.z : ad4.w);

    // phase 2: gather + inline exp + denom
    float a0 = 0.f, a1 = 0.f, a2 = 0.f, a3 = 0.f;
    float sm = 0.f;
    const size_t ch = (size_t)(lane << 2);
    for (int base = start; base < end; base += 16) {
        int m = end - base;
        if (m > 16) m = 16;
        int cv = col[base + l15];
        int sE = __shfl(cv, eloc);
        float av = 0.f;
        if (eloc < m) {
            float e = a_src[4 * (size_t)sE + q] + adq;
            e = (e > 0.f) ? e : NEG_SLOPE * e;
            av = __expf(e - mxq);
            sm += av;
        }
        int j = 0;
        for (; j + 4 <= m; j += 4) {
            int s0 = __shfl(cv, j);
            int s1 = __shfl(cv, j + 1);
            int s2 = __shfl(cv, j + 2);
            int s3 = __shfl(cv, j + 3);
            float w0 = __shfl(av, 4 * j + hd);
            float w1 = __shfl(av, 4 * j + 4 + hd);
            float w2 = __shfl(av, 4 * j + 8 + hd);
            float w3 = __shfl(av, 4 * j + 12 + hd);
            uint2 h0 = *(const uint2*)(h + (((size_t)s0) << 8) + ch);
            uint2 h1 = *(const uint2*)(h + (((size_t)s1) << 8) + ch);
            uint2 h2 = *(const uint2*)(h + (((size_t)s2) << 8) + ch);
            uint2 h3 = *(const uint2*)(h + (((size_t)s3) << 8) + ch);
            a0 = fmaf(__uint_as_float(h0.x << 16),         w0, a0);
            a1 = fmaf(__uint_as_float(h0.x & 0xffff0000u), w0, a1);
            a2 = fmaf(__uint_as_float(h0.y << 16),         w0, a2);
            a3 = fmaf(__uint_as_float(h0.y & 0xffff0000u), w0, a3);
            a0 = fmaf(__uint_as_float(h1.x << 16),         w1, a0);
            a1 = fmaf(__uint_as_float(h1.x & 0xffff0000u), w1, a1);
            a2 = fmaf(__uint_as_float(h1.y << 16),         w1, a2);
            a3 = fmaf(__uint_as_float(h1.y & 0xffff0000u), w1, a3);
            a0 = fmaf(__uint_as_float(h2.x << 16),         w2, a0);
            a1 = fmaf(__uint_as_float(h2.x & 0xffff0000u), w2, a1);
            a2 = fmaf(__uint_as_float(h2.y << 16),         w2, a2);
            a3 = fmaf(__uint_as_float(h2.y & 0xffff0000u), w2, a3);
            a0 = fmaf(__uint_as_float(h3.x << 16),         w3, a0);
            a1 = fmaf(__uint_as_float(h3.x & 0xffff0000u), w3, a1);
            a2 = fmaf(__uint_as_float(h3.y << 16),         w3, a2);
            a3 = fmaf(__uint_as_float(h3.y & 0xffff0000u), w3, a3);
        }
        for (; j < m; j++) {
            int s = __shfl(cv, j);
            float w = __shfl(av, 4 * j + hd);
            uint2 hv = *(const uint2*)(h + (((size_t)s) << 8) + ch);
            a0 = fmaf(__uint_as_float(hv.x << 16),         w, a0);
            a1 = fmaf(__uint_as_float(hv.x & 0xffff0000u), w, a1);
            a2 = fmaf(__uint_as_float(hv.y << 16),         w, a2);
            a3 = fmaf(__uint_as_float(hv.y & 0xffff0000u), w, a3);
        }
    }
    for (int off = 4; off < 64; off <<= 1) sm += __shfl_xor(sm, off);
    float inv = 1.f / __shfl(sm, hd);
    float acc[4] = {a0 * inv, a1 * inv, a2 * inv, a3 * inv};
    unsigned short ov[4];
    #pragma unroll
    for (int j = 0; j < 4; j++) {
        float v = acc[j] + g4_ld(bias, (lane << 2) + j, isf);
        v = (v > 0.f) ? v : (__expf(v) - 1.f);
        ov[j] = g4_f2bf(v);
    }
    uint2 pack;
    pack.x = (unsigned int)ov[0] | ((unsigned int)ov[1] << 16);
    pack.y = (unsigned int)ov[2] | ((unsigned int)ov[3] << 16);
    *(uint2*)(xout + ((size_t)d << 8) + (lane << 2)) = pack;
}

// ---------------------------------------------------------------------------
// Fused MLP head
// ---------------------------------------------------------------------------
__global__ __launch_bounds__(256) void g4_head2(
    const unsigned short* __restrict__ x, const void* __restrict__ w1,
    const void* __restrict__ b1, const void* __restrict__ w2,
    const void* __restrict__ b2, const int* __restrict__ flags,
    void* __restrict__ outp) {
    __shared__ float As[64][17];
    __shared__ float Bs[16][64];
    __shared__ float red[64][17];
    const int isf = flags[0];
    const int tid = threadIdx.x;
    const int bm  = blockIdx.x * 64;
    const int tx  = tid & 15;
    const int ty  = tid >> 4;
    float acc[4][4] = {};
    for (int k0 = 0; k0 < HC; k0 += 16) {
        for (int i = tid; i < 64 * 16; i += 256) {
            int m = i >> 4, kk = i & 15;
            int gm = bm + m;
            float v = 0.f;
            if (gm < NN) v = g4_bf2f(x[(size_t)gm * HC + k0 + kk]);
            As[m][kk] = v;
        }
        for (int i = tid; i < 16 * 64; i += 256) {
            int kk = i >> 6, n = i & 63;
            Bs[kk][n] = g4_ld(w1, (size_t)(k0 + kk) * 64 + n, isf);
        }
        __syncthreads();
        #pragma unroll
        for (int kk = 0; kk < 16; ++kk) {
            float a[4], b[4];
            #pragma unroll
            for (int i = 0; i < 4; i++) a[i] = As[ty * 4 + i][kk];
            #pragma unroll
            for (int j = 0; j < 4; j++) b[j] = Bs[kk][tx * 4 + j];
            #pragma unroll
            for (int i = 0; i < 4; i++)
                #pragma unroll
                for (int j = 0; j < 4; j++) acc[i][j] += a[i] * b[j];
        }
        __syncthreads();
    }
    float b1v[4], w2v[4];
    #pragma unroll
    for (int j = 0; j < 4; j++) {
        b1v[j] = g4_ld(b1, tx * 4 + j, isf);
        w2v[j] = g4_ld(w2, tx * 4 + j, isf);
    }
    #pragma unroll
    for (int i = 0; i < 4; i++) {
        float s = 0.f;
        #pragma unroll
        for (int j = 0; j < 4; j++) {
            float v = acc[i][j] + b1v[j];
            v = fmaxf(v, 0.f);
            s += v * w2v[j];
        }
        red[ty * 4 + i][tx] = s;
    }
    __syncthreads();
    if (tid < 64) {
        float s = 0.f;
        #pragma unroll
        for (int g = 0; g < 16; g++) s += red[tid][g];
        int gm = bm + tid;
        if (gm < NN) {
            float r = s + g4_ld(b2, 0, isf);
            if (isf) ((float*)outp)[gm] = r;
            else     ((unsigned short*)outp)[gm] = g4_f2bf(r);
        }
    }
}

// ---------------------------------------------------------------------------
extern "C" __attribute__((visibility("default")))
void kernel_launch(void* const* d_in, const int* in_sizes, int n_in,
                   void* d_out, int out_size, void* d_ws, size_t ws_size,
                   hipStream_t stream) {
    const void* x_in = d_in[0];
    const int*  ei   = (const int*)d_in[1];
    const void* W[3]    = {d_in[2], d_in[6], d_in[10]};
    const void* ASRC[3] = {d_in[3], d_in[7], d_in[11]};
    const void* ADST[3] = {d_in[4], d_in[8], d_in[12]};
    const void* BIAS[3] = {d_in[5], d_in[9], d_in[13]};
    const void* hw1 = d_in[14];
    const void* hb1 = d_in[15];
    const void* hw2 = d_in[16];
    const void* hb2 = d_in[17];

    char* base = (char*)d_ws;
    size_t woff = 0;
#define G4_TAKE(name, type, count) \
    type* name = (type*)(base + woff); \
    woff += (((size_t)(count)) * sizeof(type) + 255) & ~(size_t)255;
    G4_TAKE(flags,   int, 8)
    G4_TAKE(deg,     int, NN)
    G4_TAKE(cnt,     int, NN)
    G4_TAKE(tmp,     int, NN)
    G4_TAKE(partial, int, 256)
    G4_TAKE(rowptr,  int, NN + 1)
    G4_TAKE(col,     int, ETOT + 16)
    G4_TAKE(asr,     float, (size_t)NN * 4)
    G4_TAKE(adsb,    float, (size_t)NN * 4)
    G4_TAKE(Apad,    unsigned short, (size_t)(NN + 64) * 64)
    G4_TAKE(Bfrag0,  unsigned short, (size_t)HC * 64)
    G4_TAKE(Bfrag1,  unsigned short, (size_t)HC * HC)
    G4_TAKE(Bfrag2,  unsigned short, (size_t)HC * HC)
    G4_TAKE(hbuf,    unsigned short, (size_t)(NN + 64) * HC)
    G4_TAKE(xbuf,    unsigned short, (size_t)(NN + 64) * HC)
#undef G4_TAKE
    unsigned short* BF[3] = {Bfrag0, Bfrag1, Bfrag2};

    const int SCAN_BLOCKS = (NN + 255) / 256;          // 196
    const int EDGE_BLOCKS = (ETOT + 255) / 256;        // 3321
    const int WAVE_BLOCKS = (NN + 3) / 4;              // 12500
    const int TILE_BLOCKS = (NN + 63) / 64;            // 782

    g4_init<<<SCAN_BLOCKS, 256, 0, stream>>>((const unsigned int*)x_in, ei, flags,
                                             deg, cnt, (unsigned int*)d_out);

    g4_hist<<<EDGE_BLOCKS, 256, 0, stream>>>(ei, flags, deg);
    g4_scan_block<<<SCAN_BLOCKS, 256, 0, stream>>>(deg, tmp, partial);
    g4_scan_partial<<<1, 256, 0, stream>>>(partial, SCAN_BLOCKS, rowptr + NN);
    g4_scan_add<<<SCAN_BLOCKS, 256, 0, stream>>>(tmp, partial, rowptr);
    g4_fill_csr<<<EDGE_BLOCKS, 256, 0, stream>>>(ei, flags, rowptr, cnt, col);

    // layer-0 A padding to K=64 + all weight preps hoisted before the loop
    g4_aprep<<<(NN * 64 + 255) / 256, 256, 0, stream>>>(x_in, flags, Apad);
    g4_bfprep<<<(HC * 2 * 32 + 255) / 256, 256, 0, stream>>>(W[0], flags, BF[0], 61, 2);
    g4_bfprep<<<(HC * 8 * 32 + 255) / 256, 256, 0, stream>>>(W[1], flags, BF[1], HC, 8);
    g4_bfprep<<<(HC * 8 * 32 + 255) / 256, 256, 0, stream>>>(W[2], flags, BF[2], HC, 8);

    for (int l = 0; l < 3; l++) {
        if (l == 0) {
            g4_gemm3<2><<<TILE_BLOCKS, 256, 0, stream>>>(Apad, BF[0], flags, hbuf,
                ASRC[l], ADST[l], asr, adsb, NN);
        } else {
            g4_gemm3<8><<<TILE_BLOCKS, 256, 0, stream>>>(xbuf, BF[l], flags, hbuf,
                ASRC[l], ADST[l], asr, adsb, NN);
        }
        g4_gatherf<<<WAVE_BLOCKS, 256, 0, stream>>>(hbuf, asr, adsb, rowptr, col,
                                                    BIAS[l], flags, xbuf);
    }
    g4_head2<<<TILE_BLOCKS, 256, 0, stream>>>(xbuf, hw1, hb1, hw2, hb2, flags, d_out);
}